// Round 1
// baseline (4440.067 us; speedup 1.0000x reference)
//
#include <hip/hip_runtime.h>
#include <cstdint>
#include <cstddef>

// Mamba backbone decode step, fp32 baseline.
// Per layer: gemm_k<CONV> (xz proj + fused conv/silu epilogue) -> bc_kernel
// (xproj + dt + softplus + SSM + gate, block per batch row) -> gemm_k (outproj).
// 24 layers sequential, then LayerNorm.

#define BATCH 512
#define D_IN 64
#define D_MODEL 768
#define DEPTH 24
#define D_INNER 1536
#define D_STATE 16
#define D_CONV 4
#define DT_RANK 48
#define XDB_DIM 80  // DT_RANK + 2*D_STATE

__device__ __forceinline__ float sigmoidf_(float v) { return 1.f / (1.f + expf(-v)); }

// C[m,n] = sum_k A[m,k] * W[n,k]  (both row-major, K contiguous)
// BM = 16*TM, BN = 16*TN, BK = 16, 256 threads, TMxTN micro-tile.
template<int TM, int TN, bool CONV, bool BIAS>
__global__ __launch_bounds__(256) void gemm_k(
    const float* __restrict__ A,
    const float* __restrict__ W,
    const float* __restrict__ bias,
    float* __restrict__ Cout,          // plain output (M,N), or x-output when CONV
    float* __restrict__ Zout,          // z-output when CONV
    const float* __restrict__ conv_state,  // layer slice (B, D_INNER, 4)
    const float* __restrict__ conv_w,      // layer slice (D_INNER, 4)
    const float* __restrict__ conv_b,      // layer slice (D_INNER)
    int M, int N, int K)
{
    constexpr int BM = 16 * TM;
    constexpr int BN = 16 * TN;
    constexpr int BK = 16;
    __shared__ float As[BK][BM + 4];
    __shared__ float Ws[BK][BN + 4];

    const int tid = threadIdx.x;
    const int tx = tid & 15;
    const int ty = tid >> 4;
    const int bn0 = blockIdx.x * BN;
    const int bm0 = blockIdx.y * BM;

    float acc[TM][TN];
#pragma unroll
    for (int i = 0; i < TM; ++i)
#pragma unroll
        for (int j = 0; j < TN; ++j) acc[i][j] = 0.f;

    for (int k0 = 0; k0 < K; k0 += BK) {
        constexpr int NA = BM * 4;  // float4 loads for A tile
        if (NA == 256 || tid < NA) {
            int r = tid >> 2, c = (tid & 3) << 2;
            float4 a4 = *(const float4*)(A + (size_t)(bm0 + r) * K + k0 + c);
            As[c + 0][r] = a4.x; As[c + 1][r] = a4.y;
            As[c + 2][r] = a4.z; As[c + 3][r] = a4.w;
        }
        constexpr int NW = BN * 4;
        if (NW == 256 || tid < NW) {
            int r = tid >> 2, c = (tid & 3) << 2;
            float4 w4 = *(const float4*)(W + (size_t)(bn0 + r) * K + k0 + c);
            Ws[c + 0][r] = w4.x; Ws[c + 1][r] = w4.y;
            Ws[c + 2][r] = w4.z; Ws[c + 3][r] = w4.w;
        }
        __syncthreads();
#pragma unroll
        for (int kk = 0; kk < BK; ++kk) {
            float af[TM], wf[TN];
#pragma unroll
            for (int i = 0; i < TM; ++i) af[i] = As[kk][ty * TM + i];
#pragma unroll
            for (int j = 0; j < TN; ++j) wf[j] = Ws[kk][tx * TN + j];
#pragma unroll
            for (int i = 0; i < TM; ++i)
#pragma unroll
                for (int j = 0; j < TN; ++j) acc[i][j] += af[i] * wf[j];
        }
        __syncthreads();
    }

#pragma unroll
    for (int i = 0; i < TM; ++i) {
        const int bb = bm0 + ty * TM + i;
#pragma unroll
        for (int j = 0; j < TN; ++j) {
            const int n = bn0 + tx * TN + j;
            float v = acc[i][j];
            if (CONV) {
                if (n < D_INNER) {
                    // causal conv update: [cs1,cs2,cs3,v] . w + b, then silu
                    const float* cs = conv_state + ((size_t)bb * D_INNER + n) * D_CONV;
                    const float* cw = conv_w + (size_t)n * D_CONV;
                    float cv = cs[1] * cw[0] + cs[2] * cw[1] + cs[3] * cw[2]
                             + v * cw[3] + conv_b[n];
                    Cout[(size_t)bb * D_INNER + n] = cv * sigmoidf_(cv);
                } else {
                    Zout[(size_t)bb * D_INNER + (n - D_INNER)] = v;
                }
            } else {
                if (BIAS) v += bias[n];
                Cout[(size_t)bb * N + n] = v;
            }
        }
    }
}

// Fused xproj + dt-proj + softplus + SSM update + einsum + gate. One block per b.
__global__ __launch_bounds__(256) void bc_kernel(
    const float* __restrict__ x,         // (B, D_INNER) post conv+silu
    const float* __restrict__ z,         // (B, D_INNER)
    const float* __restrict__ xproj_w,   // layer (80, D_INNER)
    const float* __restrict__ dtproj_w,  // layer (D_INNER, 48)
    const float* __restrict__ dtproj_b,  // layer (D_INNER)
    const float* __restrict__ A_log,     // layer (D_INNER, 16)
    const float* __restrict__ Dp,        // layer (D_INNER)
    const float* __restrict__ ssm,       // layer (B, D_INNER, 16)
    float* __restrict__ y)               // (B, D_INNER)
{
    const int b = blockIdx.x;
    const int tid = threadIdx.x;
    __shared__ __align__(16) float xs[D_INNER];
    __shared__ float xdb[XDB_DIM];

    const float4* xrow = (const float4*)(x + (size_t)b * D_INNER);
    float4* xs4 = (float4*)xs;
    for (int i = tid; i < D_INNER / 4; i += 256) xs4[i] = xrow[i];
    __syncthreads();

    // xproj: wave-parallel dot products, coalesced W reads
    const int lane = tid & 63;
    const int wv = tid >> 6;
    for (int n = wv; n < XDB_DIM; n += 4) {
        const float4* wr = (const float4*)(xproj_w + (size_t)n * D_INNER);
        float s = 0.f;
#pragma unroll
        for (int j = 0; j < D_INNER / 4 / 64; ++j) {
            float4 w = wr[lane + 64 * j];
            float4 xv = xs4[lane + 64 * j];
            s += w.x * xv.x + w.y * xv.y + w.z * xv.z + w.w * xv.w;
        }
#pragma unroll
        for (int off = 32; off > 0; off >>= 1) s += __shfl_xor(s, off);
        if (lane == 0) xdb[n] = s;
    }
    __syncthreads();

    float Bmv[D_STATE], Cv[D_STATE];
#pragma unroll
    for (int n = 0; n < D_STATE; ++n) {
        Bmv[n] = xdb[DT_RANK + n];
        Cv[n] = xdb[DT_RANK + D_STATE + n];
    }

    for (int d = tid; d < D_INNER; d += 256) {
        // dt = softplus( xdb[0:48] . dtproj_w[d,:] + dtproj_b[d] )
        const float4* dtw = (const float4*)(dtproj_w + (size_t)d * DT_RANK);
        float s = 0.f;
#pragma unroll
        for (int j = 0; j < DT_RANK / 4; ++j) {
            float4 w = dtw[j];
            s += w.x * xdb[4 * j + 0] + w.y * xdb[4 * j + 1]
               + w.z * xdb[4 * j + 2] + w.w * xdb[4 * j + 3];
        }
        s += dtproj_b[d];
        float dt = fmaxf(s, 0.f) + log1pf(expf(-fabsf(s)));
        float xv = xs[d];
        float dtx = dt * xv;

        const float4* ssp = (const float4*)(ssm + ((size_t)b * D_INNER + d) * D_STATE);
        const float4* alp = (const float4*)(A_log + (size_t)d * D_STATE);
        float yacc = 0.f;
#pragma unroll
        for (int q = 0; q < 4; ++q) {
            float4 al = alp[q];
            float4 sv = ssp[q];
            float e0 = expf(-dt * expf(al.x));
            float e1 = expf(-dt * expf(al.y));
            float e2 = expf(-dt * expf(al.z));
            float e3 = expf(-dt * expf(al.w));
            yacc += (sv.x * e0 + dtx * Bmv[4 * q + 0]) * Cv[4 * q + 0];
            yacc += (sv.y * e1 + dtx * Bmv[4 * q + 1]) * Cv[4 * q + 1];
            yacc += (sv.z * e2 + dtx * Bmv[4 * q + 2]) * Cv[4 * q + 2];
            yacc += (sv.w * e3 + dtx * Bmv[4 * q + 3]) * Cv[4 * q + 3];
        }
        yacc += Dp[d] * xv;
        float zv = z[(size_t)b * D_INNER + d];
        y[(size_t)b * D_INNER + d] = yacc * (zv * sigmoidf_(zv));
    }
}

__global__ __launch_bounds__(256) void ln_kernel(
    const float* __restrict__ h, const float* __restrict__ g,
    const float* __restrict__ be, float* __restrict__ out)
{
    const int b = blockIdx.x;
    const int tid = threadIdx.x;
    float v[3];
#pragma unroll
    for (int j = 0; j < 3; ++j) v[j] = h[(size_t)b * D_MODEL + tid + j * 256];
    float s = v[0] + v[1] + v[2];
    float s2 = v[0] * v[0] + v[1] * v[1] + v[2] * v[2];
#pragma unroll
    for (int off = 32; off > 0; off >>= 1) {
        s += __shfl_xor(s, off);
        s2 += __shfl_xor(s2, off);
    }
    __shared__ float red[8];
    const int lane = tid & 63, wv = tid >> 6;
    if (lane == 0) { red[wv] = s; red[4 + wv] = s2; }
    __syncthreads();
    s = red[0] + red[1] + red[2] + red[3];
    s2 = red[4] + red[5] + red[6] + red[7];
    const float mu = s * (1.f / D_MODEL);
    const float var = s2 * (1.f / D_MODEL) - mu * mu;
    const float inv = 1.f / sqrtf(var + 1e-5f);
#pragma unroll
    for (int j = 0; j < 3; ++j) {
        int c = tid + j * 256;
        out[(size_t)b * D_MODEL + c] = (v[j] - mu) * inv * g[c] + be[c];
    }
}

extern "C" void kernel_launch(void* const* d_in, const int* in_sizes, int n_in,
                              void* d_out, int out_size, void* d_ws, size_t ws_size,
                              hipStream_t stream)
{
    const float* x_t        = (const float*)d_in[0];
    const float* in_w       = (const float*)d_in[1];
    const float* in_b       = (const float*)d_in[2];
    const float* xz_w       = (const float*)d_in[3];
    const float* conv_w     = (const float*)d_in[4];
    const float* conv_b     = (const float*)d_in[5];
    const float* xproj_w    = (const float*)d_in[6];
    const float* dtproj_w   = (const float*)d_in[7];
    const float* dtproj_b   = (const float*)d_in[8];
    const float* A_log      = (const float*)d_in[9];
    const float* Dvec       = (const float*)d_in[10];
    const float* outproj_w  = (const float*)d_in[11];
    const float* conv_state = (const float*)d_in[12];
    const float* ssm_state  = (const float*)d_in[13];
    const float* ln_g       = (const float*)d_in[14];
    const float* ln_b       = (const float*)d_in[15];

    float* ws = (float*)d_ws;
    float* h = ws;                               // B * D_MODEL
    float* x = h + (size_t)BATCH * D_MODEL;      // B * D_INNER
    float* z = x + (size_t)BATCH * D_INNER;      // B * D_INNER
    float* y = z + (size_t)BATCH * D_INNER;      // B * D_INNER

    dim3 blk(256);

    // in_proj: h = x_t @ in_w^T + in_b   (M=512, N=768, K=64)
    gemm_k<4, 4, false, true><<<dim3(D_MODEL / 64, BATCH / 64), blk, 0, stream>>>(
        x_t, in_w, in_b, h, nullptr, nullptr, nullptr, nullptr,
        BATCH, D_MODEL, D_IN);

    for (int l = 0; l < DEPTH; ++l) {
        const float* xzw = xz_w + (size_t)l * 2 * D_INNER * D_MODEL;
        const float* csl = conv_state + (size_t)l * BATCH * D_INNER * D_CONV;
        const float* cwl = conv_w + (size_t)l * D_INNER * D_CONV;
        const float* cbl = conv_b + (size_t)l * D_INNER;
        const float* xpl = xproj_w + (size_t)l * XDB_DIM * D_INNER;
        const float* dwl = dtproj_w + (size_t)l * D_INNER * DT_RANK;
        const float* dbl = dtproj_b + (size_t)l * D_INNER;
        const float* all = A_log + (size_t)l * D_INNER * D_STATE;
        const float* dpl = Dvec + (size_t)l * D_INNER;
        const float* ssl = ssm_state + (size_t)l * BATCH * D_INNER * D_STATE;
        const float* opl = outproj_w + (size_t)l * D_MODEL * D_INNER;

        // xz = h @ xz_w^T, fused conv+silu epilogue  (M=512, N=3072, K=768)
        gemm_k<4, 4, true, false><<<dim3(2 * D_INNER / 64, BATCH / 64), blk, 0, stream>>>(
            h, xzw, nullptr, x, z, csl, cwl, cbl,
            BATCH, 2 * D_INNER, D_MODEL);

        // xproj + dt + ssm + gate -> y
        bc_kernel<<<dim3(BATCH), blk, 0, stream>>>(
            x, z, xpl, dwl, dbl, all, dpl, ssl, y);

        // h = y @ outproj_w^T  (M=512, N=768, K=1536), 32x64 tiles for more blocks
        gemm_k<2, 4, false, false><<<dim3(D_MODEL / 64, BATCH / 32), blk, 0, stream>>>(
            y, opl, nullptr, h, nullptr, nullptr, nullptr, nullptr,
            BATCH, D_MODEL, D_INNER);
    }

    ln_kernel<<<dim3(BATCH), blk, 0, stream>>>(h, ln_g, ln_b, (float*)d_out);
}

// Round 2
// 2663.075 us; speedup vs baseline: 1.6673x; 1.6673x over previous
//
#include <hip/hip_runtime.h>
#include <cstdint>
#include <cstddef>

#define BATCH 512
#define D_IN 64
#define D_MODEL 768
#define DEPTH 24
#define D_INNER 1536
#define D_STATE 16
#define D_CONV 4
#define DT_RANK 48
#define XDB_DIM 80  // DT_RANK + 2*D_STATE

typedef __bf16 bf16x8 __attribute__((ext_vector_type(8)));
typedef unsigned short ushortx8 __attribute__((ext_vector_type(8)));
typedef float f32x4 __attribute__((ext_vector_type(4)));

__device__ __forceinline__ float sigmoidf_(float v) { return 1.f / (1.f + expf(-v)); }

// Truncation-based fp32 -> bf16 hi/lo split. hi = trunc16(f) (exact residual),
// lo = trunc16(f - hi). Missing mass ~2^-16 relative; products use hh+hl+lh.
__device__ __forceinline__ void split1(float f, unsigned short& h, unsigned short& l) {
    unsigned int u = __float_as_uint(f);
    unsigned int uh = u & 0xffff0000u;
    h = (unsigned short)(uh >> 16);
    float r = f - __uint_as_float(uh);
    l = (unsigned short)(__float_as_uint(r) >> 16);
}

// C(M,N) = A(M,K) @ W(N,K)^T via bf16x3 MFMA. 64x64 tile, 4 waves of 32x32.
// LDS row layout: [64 rows][64 shorts] = [hi 32 | lo 32], 16B-slot XOR swizzle
// (slot ^= row&7) -> conflict-free b128 reads/writes. Double-buffered, one
// barrier per BK=32 step.
template<bool CONV>
__global__ __launch_bounds__(256) void mfma_gemm(
    const float* __restrict__ A,
    const float* __restrict__ W,
    float* __restrict__ Cout,              // (M,N) or x-output when CONV
    float* __restrict__ Zout,              // z-output when CONV
    const float* __restrict__ conv_state,  // layer (B, D_INNER, 4)
    const float* __restrict__ conv_w,      // layer (D_INNER, 4)
    const float* __restrict__ conv_b,      // layer (D_INNER)
    int N, int K)
{
    __shared__ __align__(16) unsigned short As[2][64 * 64];
    __shared__ __align__(16) unsigned short Bs[2][64 * 64];

    const int t = threadIdx.x;
    const int bn0 = blockIdx.x * 64;
    const int bm0 = blockIdx.y * 64;
    // staging: thread -> (row, 8-float chunk)
    const int sr = t >> 2;            // 0..63
    const int sc = (t & 3) << 3;      // 0,8,16,24
    const int lane = t & 63;
    const int wv = t >> 6;            // wave 0..3
    const int wm = wv >> 1, wn = wv & 1;
    const int ln15 = lane & 15, kq = lane >> 4;  // frag row / k-quarter

    const float* Aptr = A + (size_t)(bm0 + sr) * K + sc;
    const float* Wptr = W + (size_t)(bn0 + sr) * K + sc;

    f32x4 acc[2][2];
#pragma unroll
    for (int m = 0; m < 2; ++m)
#pragma unroll
        for (int n = 0; n < 2; ++n) acc[m][n] = (f32x4){0.f, 0.f, 0.f, 0.f};

    auto stage = [&](float4 x0, float4 x1, unsigned short* S) {
        float f[8] = {x0.x, x0.y, x0.z, x0.w, x1.x, x1.y, x1.z, x1.w};
        ushortx8 hi, lo;
#pragma unroll
        for (int j = 0; j < 8; ++j) {
            unsigned short h, l;
            split1(f[j], h, l);
            hi[j] = h; lo[j] = l;
        }
        const int s0 = sc >> 3;  // 0..3
        const int sw = sr & 7;
        *(ushortx8*)&S[sr * 64 + ((s0 ^ sw) << 3)] = hi;
        *(ushortx8*)&S[sr * 64 + (((s0 + 4) ^ sw) << 3)] = lo;
    };

    const int nk = K >> 5;

    // prologue: stage k-step 0
    float4 a0 = *(const float4*)(Aptr);
    float4 a1 = *(const float4*)(Aptr + 4);
    float4 b0 = *(const float4*)(Wptr);
    float4 b1 = *(const float4*)(Wptr + 4);
    stage(a0, a1, As[0]);
    stage(b0, b1, Bs[0]);

    for (int kb = 0; kb < nk; ++kb) {
        __syncthreads();
        const int cur = kb & 1;
        if (kb + 1 < nk) {
            const float* Ap = Aptr + ((kb + 1) << 5);
            const float* Wp = Wptr + ((kb + 1) << 5);
            a0 = *(const float4*)(Ap);
            a1 = *(const float4*)(Ap + 4);
            b0 = *(const float4*)(Wp);
            b1 = *(const float4*)(Wp + 4);
        }
        bf16x8 ah[2], al[2], bh[2], bl[2];
#pragma unroll
        for (int m = 0; m < 2; ++m) {
            const int r = wm * 32 + m * 16 + ln15;
            const int base = r * 64;
            const int sw = r & 7;
            ah[m] = __builtin_bit_cast(bf16x8, *(ushortx8*)&As[cur][base + ((kq ^ sw) << 3)]);
            al[m] = __builtin_bit_cast(bf16x8, *(ushortx8*)&As[cur][base + (((kq + 4) ^ sw) << 3)]);
        }
#pragma unroll
        for (int n = 0; n < 2; ++n) {
            const int r = wn * 32 + n * 16 + ln15;
            const int base = r * 64;
            const int sw = r & 7;
            bh[n] = __builtin_bit_cast(bf16x8, *(ushortx8*)&Bs[cur][base + ((kq ^ sw) << 3)]);
            bl[n] = __builtin_bit_cast(bf16x8, *(ushortx8*)&Bs[cur][base + (((kq + 4) ^ sw) << 3)]);
        }
#pragma unroll
        for (int m = 0; m < 2; ++m)
#pragma unroll
            for (int n = 0; n < 2; ++n) {
                acc[m][n] = __builtin_amdgcn_mfma_f32_16x16x32_bf16(ah[m], bh[n], acc[m][n], 0, 0, 0);
                acc[m][n] = __builtin_amdgcn_mfma_f32_16x16x32_bf16(ah[m], bl[n], acc[m][n], 0, 0, 0);
                acc[m][n] = __builtin_amdgcn_mfma_f32_16x16x32_bf16(al[m], bh[n], acc[m][n], 0, 0, 0);
            }
        if (kb + 1 < nk) {
            stage(a0, a1, As[cur ^ 1]);
            stage(b0, b1, Bs[cur ^ 1]);
        }
    }

    // epilogue: C/D frag mapping col=lane&15, row=(lane>>4)*4+j
#pragma unroll
    for (int m = 0; m < 2; ++m) {
#pragma unroll
        for (int n = 0; n < 2; ++n) {
            const int col = bn0 + wn * 32 + n * 16 + ln15;
            const int row0 = bm0 + wm * 32 + m * 16 + kq * 4;
            f32x4 v = acc[m][n];
            if (CONV) {
                if (col < D_INNER) {
                    const float4 cwv = *(const float4*)(conv_w + (size_t)col * 4);
                    const float cbv = conv_b[col];
#pragma unroll
                    for (int j = 0; j < 4; ++j) {
                        const int row = row0 + j;
                        const float4 csv = *(const float4*)(conv_state + ((size_t)row * D_INNER + col) * 4);
                        float c = csv.y * cwv.x + csv.z * cwv.y + csv.w * cwv.z
                                + v[j] * cwv.w + cbv;
                        Cout[(size_t)row * D_INNER + col] = c * sigmoidf_(c);
                    }
                } else {
#pragma unroll
                    for (int j = 0; j < 4; ++j)
                        Zout[(size_t)(row0 + j) * D_INNER + (col - D_INNER)] = v[j];
                }
            } else {
#pragma unroll
                for (int j = 0; j < 4; ++j)
                    Cout[(size_t)(row0 + j) * N + col] = v[j];
            }
        }
    }
}

// fp32 tiled GEMM, used only for in_proj (K=64, tiny).
template<int TM, int TN, bool BIAS>
__global__ __launch_bounds__(256) void gemm_k(
    const float* __restrict__ A,
    const float* __restrict__ W,
    const float* __restrict__ bias,
    float* __restrict__ Cout,
    int M, int N, int K)
{
    constexpr int BM = 16 * TM;
    constexpr int BN = 16 * TN;
    constexpr int BK = 16;
    __shared__ float As[BK][BM + 4];
    __shared__ float Ws[BK][BN + 4];

    const int tid = threadIdx.x;
    const int tx = tid & 15;
    const int ty = tid >> 4;
    const int bn0 = blockIdx.x * BN;
    const int bm0 = blockIdx.y * BM;

    float acc[TM][TN];
#pragma unroll
    for (int i = 0; i < TM; ++i)
#pragma unroll
        for (int j = 0; j < TN; ++j) acc[i][j] = 0.f;

    for (int k0 = 0; k0 < K; k0 += BK) {
        {
            int r = tid >> 2, c = (tid & 3) << 2;
            float4 a4 = *(const float4*)(A + (size_t)(bm0 + r) * K + k0 + c);
            As[c + 0][r] = a4.x; As[c + 1][r] = a4.y;
            As[c + 2][r] = a4.z; As[c + 3][r] = a4.w;
            float4 w4 = *(const float4*)(W + (size_t)(bn0 + r) * K + k0 + c);
            Ws[c + 0][r] = w4.x; Ws[c + 1][r] = w4.y;
            Ws[c + 2][r] = w4.z; Ws[c + 3][r] = w4.w;
        }
        __syncthreads();
#pragma unroll
        for (int kk = 0; kk < BK; ++kk) {
            float af[TM], wf[TN];
#pragma unroll
            for (int i = 0; i < TM; ++i) af[i] = As[kk][ty * TM + i];
#pragma unroll
            for (int j = 0; j < TN; ++j) wf[j] = Ws[kk][tx * TN + j];
#pragma unroll
            for (int i = 0; i < TM; ++i)
#pragma unroll
                for (int j = 0; j < TN; ++j) acc[i][j] += af[i] * wf[j];
        }
        __syncthreads();
    }

#pragma unroll
    for (int i = 0; i < TM; ++i) {
        const int bb = bm0 + ty * TM + i;
#pragma unroll
        for (int j = 0; j < TN; ++j) {
            const int n = bn0 + tx * TN + j;
            float v = acc[i][j];
            if (BIAS) v += bias[n];
            Cout[(size_t)bb * N + n] = v;
        }
    }
}

// Fused xproj + dt-proj + softplus + SSM update + einsum + gate. One block per b.
__global__ __launch_bounds__(256) void bc_kernel(
    const float* __restrict__ x,
    const float* __restrict__ z,
    const float* __restrict__ xproj_w,
    const float* __restrict__ dtproj_w,
    const float* __restrict__ dtproj_b,
    const float* __restrict__ A_log,
    const float* __restrict__ Dp,
    const float* __restrict__ ssm,
    float* __restrict__ y)
{
    const int b = blockIdx.x;
    const int tid = threadIdx.x;
    __shared__ __align__(16) float xs[D_INNER];
    __shared__ float xdb[XDB_DIM];

    const float4* xrow = (const float4*)(x + (size_t)b * D_INNER);
    float4* xs4 = (float4*)xs;
    for (int i = tid; i < D_INNER / 4; i += 256) xs4[i] = xrow[i];
    __syncthreads();

    const int lane = tid & 63;
    const int wv = tid >> 6;
    for (int n = wv; n < XDB_DIM; n += 4) {
        const float4* wr = (const float4*)(xproj_w + (size_t)n * D_INNER);
        float s = 0.f;
#pragma unroll
        for (int j = 0; j < D_INNER / 4 / 64; ++j) {
            float4 w = wr[lane + 64 * j];
            float4 xv = xs4[lane + 64 * j];
            s += w.x * xv.x + w.y * xv.y + w.z * xv.z + w.w * xv.w;
        }
#pragma unroll
        for (int off = 32; off > 0; off >>= 1) s += __shfl_xor(s, off);
        if (lane == 0) xdb[n] = s;
    }
    __syncthreads();

    float Bmv[D_STATE], Cv[D_STATE];
#pragma unroll
    for (int n = 0; n < D_STATE; ++n) {
        Bmv[n] = xdb[DT_RANK + n];
        Cv[n] = xdb[DT_RANK + D_STATE + n];
    }

    for (int d = tid; d < D_INNER; d += 256) {
        const float4* dtw = (const float4*)(dtproj_w + (size_t)d * DT_RANK);
        float s = 0.f;
#pragma unroll
        for (int j = 0; j < DT_RANK / 4; ++j) {
            float4 w = dtw[j];
            s += w.x * xdb[4 * j + 0] + w.y * xdb[4 * j + 1]
               + w.z * xdb[4 * j + 2] + w.w * xdb[4 * j + 3];
        }
        s += dtproj_b[d];
        float dt = fmaxf(s, 0.f) + log1pf(expf(-fabsf(s)));
        float xv = xs[d];
        float dtx = dt * xv;

        const float4* ssp = (const float4*)(ssm + ((size_t)b * D_INNER + d) * D_STATE);
        const float4* alp = (const float4*)(A_log + (size_t)d * D_STATE);
        float yacc = 0.f;
#pragma unroll
        for (int q = 0; q < 4; ++q) {
            float4 al = alp[q];
            float4 sv = ssp[q];
            float e0 = expf(-dt * expf(al.x));
            float e1 = expf(-dt * expf(al.y));
            float e2 = expf(-dt * expf(al.z));
            float e3 = expf(-dt * expf(al.w));
            yacc += (sv.x * e0 + dtx * Bmv[4 * q + 0]) * Cv[4 * q + 0];
            yacc += (sv.y * e1 + dtx * Bmv[4 * q + 1]) * Cv[4 * q + 1];
            yacc += (sv.z * e2 + dtx * Bmv[4 * q + 2]) * Cv[4 * q + 2];
            yacc += (sv.w * e3 + dtx * Bmv[4 * q + 3]) * Cv[4 * q + 3];
        }
        yacc += Dp[d] * xv;
        float zv = z[(size_t)b * D_INNER + d];
        y[(size_t)b * D_INNER + d] = yacc * (zv * sigmoidf_(zv));
    }
}

__global__ __launch_bounds__(256) void ln_kernel(
    const float* __restrict__ h, const float* __restrict__ g,
    const float* __restrict__ be, float* __restrict__ out)
{
    const int b = blockIdx.x;
    const int tid = threadIdx.x;
    float v[3];
#pragma unroll
    for (int j = 0; j < 3; ++j) v[j] = h[(size_t)b * D_MODEL + tid + j * 256];
    float s = v[0] + v[1] + v[2];
    float s2 = v[0] * v[0] + v[1] * v[1] + v[2] * v[2];
#pragma unroll
    for (int off = 32; off > 0; off >>= 1) {
        s += __shfl_xor(s, off);
        s2 += __shfl_xor(s2, off);
    }
    __shared__ float red[8];
    const int lane = tid & 63, wv = tid >> 6;
    if (lane == 0) { red[wv] = s; red[4 + wv] = s2; }
    __syncthreads();
    s = red[0] + red[1] + red[2] + red[3];
    s2 = red[4] + red[5] + red[6] + red[7];
    const float mu = s * (1.f / D_MODEL);
    const float var = s2 * (1.f / D_MODEL) - mu * mu;
    const float inv = 1.f / sqrtf(var + 1e-5f);
#pragma unroll
    for (int j = 0; j < 3; ++j) {
        int c = tid + j * 256;
        out[(size_t)b * D_MODEL + c] = (v[j] - mu) * inv * g[c] + be[c];
    }
}

extern "C" void kernel_launch(void* const* d_in, const int* in_sizes, int n_in,
                              void* d_out, int out_size, void* d_ws, size_t ws_size,
                              hipStream_t stream)
{
    const float* x_t        = (const float*)d_in[0];
    const float* in_w       = (const float*)d_in[1];
    const float* in_b       = (const float*)d_in[2];
    const float* xz_w       = (const float*)d_in[3];
    const float* conv_w     = (const float*)d_in[4];
    const float* conv_b     = (const float*)d_in[5];
    const float* xproj_w    = (const float*)d_in[6];
    const float* dtproj_w   = (const float*)d_in[7];
    const float* dtproj_b   = (const float*)d_in[8];
    const float* A_log      = (const float*)d_in[9];
    const float* Dvec       = (const float*)d_in[10];
    const float* outproj_w  = (const float*)d_in[11];
    const float* conv_state = (const float*)d_in[12];
    const float* ssm_state  = (const float*)d_in[13];
    const float* ln_g       = (const float*)d_in[14];
    const float* ln_b       = (const float*)d_in[15];

    float* ws = (float*)d_ws;
    float* h = ws;                               // B * D_MODEL
    float* x = h + (size_t)BATCH * D_MODEL;      // B * D_INNER
    float* z = x + (size_t)BATCH * D_INNER;      // B * D_INNER
    float* y = z + (size_t)BATCH * D_INNER;      // B * D_INNER

    dim3 blk(256);

    // in_proj: h = x_t @ in_w^T + in_b   (M=512, N=768, K=64)
    gemm_k<4, 4, true><<<dim3(D_MODEL / 64, BATCH / 64), blk, 0, stream>>>(
        x_t, in_w, in_b, h, BATCH, D_MODEL, D_IN);

    for (int l = 0; l < DEPTH; ++l) {
        const float* xzw = xz_w + (size_t)l * 2 * D_INNER * D_MODEL;
        const float* csl = conv_state + (size_t)l * BATCH * D_INNER * D_CONV;
        const float* cwl = conv_w + (size_t)l * D_INNER * D_CONV;
        const float* cbl = conv_b + (size_t)l * D_INNER;
        const float* xpl = xproj_w + (size_t)l * XDB_DIM * D_INNER;
        const float* dwl = dtproj_w + (size_t)l * D_INNER * DT_RANK;
        const float* dbl = dtproj_b + (size_t)l * D_INNER;
        const float* all = A_log + (size_t)l * D_INNER * D_STATE;
        const float* dpl = Dvec + (size_t)l * D_INNER;
        const float* ssl = ssm_state + (size_t)l * BATCH * D_INNER * D_STATE;
        const float* opl = outproj_w + (size_t)l * D_MODEL * D_INNER;

        // xz = h @ xz_w^T with fused conv+silu epilogue (M=512, N=3072, K=768)
        mfma_gemm<true><<<dim3(2 * D_INNER / 64, BATCH / 64), blk, 0, stream>>>(
            h, xzw, x, z, csl, cwl, cbl, 2 * D_INNER, D_MODEL);

        // xproj + dt + ssm + gate -> y
        bc_kernel<<<dim3(BATCH), blk, 0, stream>>>(
            x, z, xpl, dwl, dbl, all, dpl, ssl, y);

        // h = y @ outproj_w^T  (M=512, N=768, K=1536)
        mfma_gemm<false><<<dim3(D_MODEL / 64, BATCH / 64), blk, 0, stream>>>(
            y, opl, h, nullptr, nullptr, nullptr, nullptr, D_MODEL, D_INNER);
    }

    ln_kernel<<<dim3(BATCH), blk, 0, stream>>>(h, ln_g, ln_b, (float*)d_out);
}

// Round 3
// 2467.230 us; speedup vs baseline: 1.7996x; 1.0794x over previous
//
#include <hip/hip_runtime.h>
#include <cstdint>
#include <cstddef>

#define BATCH 512
#define D_IN 64
#define D_MODEL 768
#define DEPTH 24
#define D_INNER 1536
#define D_STATE 16
#define D_CONV 4
#define DT_RANK 48
#define XDB_DIM 80  // DT_RANK + 2*D_STATE

typedef __bf16 bf16x8 __attribute__((ext_vector_type(8)));
typedef unsigned short ushortx8 __attribute__((ext_vector_type(8)));
typedef float f32x4 __attribute__((ext_vector_type(4)));
typedef unsigned short ushort_t;

__device__ __forceinline__ float sigmoidf_(float v) { return 1.f / (1.f + expf(-v)); }

// Truncation-based fp32 -> bf16 hi/lo split (same numerics as round 2).
__device__ __forceinline__ void split1(float f, unsigned short& h, unsigned short& l) {
    unsigned int u = __float_as_uint(f);
    unsigned int uh = u & 0xffff0000u;
    h = (unsigned short)(uh >> 16);
    float r = f - __uint_as_float(uh);
    l = (unsigned short)(__float_as_uint(r) >> 16);
}

// One-time: split fp32 weight tensor into bf16 hi/lo planes. n8 = count of 8-float groups.
__global__ __launch_bounds__(256) void prep_split(
    const float* __restrict__ src, ushort_t* __restrict__ hi, ushort_t* __restrict__ lo,
    long n8)
{
    long i = (long)blockIdx.x * 256 + threadIdx.x;
    const long stride = (long)gridDim.x * 256;
    for (; i < n8; i += stride) {
        float4 a = *(const float4*)(src + i * 8);
        float4 b = *(const float4*)(src + i * 8 + 4);
        float f[8] = {a.x, a.y, a.z, a.w, b.x, b.y, b.z, b.w};
        ushortx8 h, l;
#pragma unroll
        for (int j = 0; j < 8; ++j) {
            unsigned short hh, ll;
            split1(f[j], hh, ll);
            h[j] = hh; l[j] = ll;
        }
        *(ushortx8*)(hi + i * 8) = h;
        *(ushortx8*)(lo + i * 8) = l;
    }
}

// C(M,N) = A(M,K) @ W(N,K)^T via bf16x3 MFMA with PRE-SPLIT hi/lo bf16 planes.
// 64x64 tile, 4 waves of 32x32, BK=32, double-buffered LDS, slot-XOR swizzle.
template<bool CONV>
__global__ __launch_bounds__(256) void mfma_gemm2(
    const ushort_t* __restrict__ Ahi, const ushort_t* __restrict__ Alo,
    const ushort_t* __restrict__ Whi, const ushort_t* __restrict__ Wlo,
    float* __restrict__ Cout,              // (M,N) or x-output when CONV
    float* __restrict__ Zout,              // z-output when CONV
    ushort_t* __restrict__ Chi,            // split outputs (non-CONV)
    ushort_t* __restrict__ Clo,
    const float* __restrict__ conv_state,  // layer (B, D_INNER, 4)
    const float* __restrict__ conv_w,      // layer (D_INNER, 4)
    const float* __restrict__ conv_b,      // layer (D_INNER)
    int N, int K)
{
    __shared__ __align__(16) unsigned short As[2][64 * 64];
    __shared__ __align__(16) unsigned short Bs[2][64 * 64];

    const int t = threadIdx.x;
    const int bn0 = blockIdx.x * 64;
    const int bm0 = blockIdx.y * 64;
    const int sr = t >> 2;            // staging row 0..63
    const int s0 = t & 3;             // staging 8-elem chunk 0..3
    const int lane = t & 63;
    const int wv = t >> 6;
    const int wm = wv >> 1, wn = wv & 1;
    const int ln15 = lane & 15, kq = lane >> 4;

    const ushort_t* Ah = Ahi + (size_t)(bm0 + sr) * K + s0 * 8;
    const ushort_t* Al = Alo + (size_t)(bm0 + sr) * K + s0 * 8;
    const ushort_t* Wh = Whi + (size_t)(bn0 + sr) * K + s0 * 8;
    const ushort_t* Wl = Wlo + (size_t)(bn0 + sr) * K + s0 * 8;

    f32x4 acc[2][2];
#pragma unroll
    for (int m = 0; m < 2; ++m)
#pragma unroll
        for (int n = 0; n < 2; ++n) acc[m][n] = (f32x4){0.f, 0.f, 0.f, 0.f};

    const int sw = sr & 7;
    auto stage = [&](ushortx8 hi, ushortx8 lo, unsigned short* S) {
        *(ushortx8*)&S[sr * 64 + ((s0 ^ sw) << 3)] = hi;
        *(ushortx8*)&S[sr * 64 + (((s0 + 4) ^ sw) << 3)] = lo;
    };

    const int nk = K >> 5;

    ushortx8 pah = *(const ushortx8*)Ah;
    ushortx8 pal = *(const ushortx8*)Al;
    ushortx8 pwh = *(const ushortx8*)Wh;
    ushortx8 pwl = *(const ushortx8*)Wl;
    stage(pah, pal, As[0]);
    stage(pwh, pwl, Bs[0]);

    for (int kb = 0; kb < nk; ++kb) {
        __syncthreads();
        const int cur = kb & 1;
        if (kb + 1 < nk) {
            const int ko = (kb + 1) << 5;
            pah = *(const ushortx8*)(Ah + ko);
            pal = *(const ushortx8*)(Al + ko);
            pwh = *(const ushortx8*)(Wh + ko);
            pwl = *(const ushortx8*)(Wl + ko);
        }
        bf16x8 ah[2], al[2], bh[2], bl[2];
#pragma unroll
        for (int m = 0; m < 2; ++m) {
            const int r = wm * 32 + m * 16 + ln15;
            const int base = r * 64;
            const int rs = r & 7;
            ah[m] = __builtin_bit_cast(bf16x8, *(ushortx8*)&As[cur][base + ((kq ^ rs) << 3)]);
            al[m] = __builtin_bit_cast(bf16x8, *(ushortx8*)&As[cur][base + (((kq + 4) ^ rs) << 3)]);
        }
#pragma unroll
        for (int n = 0; n < 2; ++n) {
            const int r = wn * 32 + n * 16 + ln15;
            const int base = r * 64;
            const int rs = r & 7;
            bh[n] = __builtin_bit_cast(bf16x8, *(ushortx8*)&Bs[cur][base + ((kq ^ rs) << 3)]);
            bl[n] = __builtin_bit_cast(bf16x8, *(ushortx8*)&Bs[cur][base + (((kq + 4) ^ rs) << 3)]);
        }
#pragma unroll
        for (int m = 0; m < 2; ++m)
#pragma unroll
            for (int n = 0; n < 2; ++n) {
                acc[m][n] = __builtin_amdgcn_mfma_f32_16x16x32_bf16(ah[m], bh[n], acc[m][n], 0, 0, 0);
                acc[m][n] = __builtin_amdgcn_mfma_f32_16x16x32_bf16(ah[m], bl[n], acc[m][n], 0, 0, 0);
                acc[m][n] = __builtin_amdgcn_mfma_f32_16x16x32_bf16(al[m], bh[n], acc[m][n], 0, 0, 0);
            }
        if (kb + 1 < nk) {
            stage(pah, pal, As[cur ^ 1]);
            stage(pwh, pwl, Bs[cur ^ 1]);
        }
    }

    // epilogue: C/D frag mapping col=lane&15, row=(lane>>4)*4+j
#pragma unroll
    for (int m = 0; m < 2; ++m) {
#pragma unroll
        for (int n = 0; n < 2; ++n) {
            const int col = bn0 + wn * 32 + n * 16 + ln15;
            const int row0 = bm0 + wm * 32 + m * 16 + kq * 4;
            f32x4 v = acc[m][n];
            if (CONV) {
                if (col < D_INNER) {
                    const float4 cwv = *(const float4*)(conv_w + (size_t)col * 4);
                    const float cbv = conv_b[col];
#pragma unroll
                    for (int j = 0; j < 4; ++j) {
                        const int row = row0 + j;
                        const float4 csv = *(const float4*)(conv_state + ((size_t)row * D_INNER + col) * 4);
                        float c = csv.y * cwv.x + csv.z * cwv.y + csv.w * cwv.z
                                + v[j] * cwv.w + cbv;
                        Cout[(size_t)row * D_INNER + col] = c * sigmoidf_(c);
                    }
                } else {
#pragma unroll
                    for (int j = 0; j < 4; ++j)
                        Zout[(size_t)(row0 + j) * D_INNER + (col - D_INNER)] = v[j];
                }
            } else {
#pragma unroll
                for (int j = 0; j < 4; ++j) {
                    const size_t idx = (size_t)(row0 + j) * N + col;
                    float val = v[j];
                    Cout[idx] = val;
                    unsigned short hh, ll;
                    split1(val, hh, ll);
                    Chi[idx] = hh;
                    Clo[idx] = ll;
                }
            }
        }
    }
}

// fp32 tiled GEMM for in_proj (K=64); epilogue writes h + split planes.
template<int TM, int TN>
__global__ __launch_bounds__(256) void gemm_k(
    const float* __restrict__ A,
    const float* __restrict__ W,
    const float* __restrict__ bias,
    float* __restrict__ Cout,
    ushort_t* __restrict__ Chi, ushort_t* __restrict__ Clo,
    int M, int N, int K)
{
    constexpr int BM = 16 * TM;
    constexpr int BN = 16 * TN;
    constexpr int BK = 16;
    __shared__ float As[BK][BM + 4];
    __shared__ float Ws[BK][BN + 4];

    const int tid = threadIdx.x;
    const int tx = tid & 15;
    const int ty = tid >> 4;
    const int bn0 = blockIdx.x * BN;
    const int bm0 = blockIdx.y * BM;

    float acc[TM][TN];
#pragma unroll
    for (int i = 0; i < TM; ++i)
#pragma unroll
        for (int j = 0; j < TN; ++j) acc[i][j] = 0.f;

    for (int k0 = 0; k0 < K; k0 += BK) {
        {
            int r = tid >> 2, c = (tid & 3) << 2;
            float4 a4 = *(const float4*)(A + (size_t)(bm0 + r) * K + k0 + c);
            As[c + 0][r] = a4.x; As[c + 1][r] = a4.y;
            As[c + 2][r] = a4.z; As[c + 3][r] = a4.w;
            float4 w4 = *(const float4*)(W + (size_t)(bn0 + r) * K + k0 + c);
            Ws[c + 0][r] = w4.x; Ws[c + 1][r] = w4.y;
            Ws[c + 2][r] = w4.z; Ws[c + 3][r] = w4.w;
        }
        __syncthreads();
#pragma unroll
        for (int kk = 0; kk < BK; ++kk) {
            float af[TM], wf[TN];
#pragma unroll
            for (int i = 0; i < TM; ++i) af[i] = As[kk][ty * TM + i];
#pragma unroll
            for (int j = 0; j < TN; ++j) wf[j] = Ws[kk][tx * TN + j];
#pragma unroll
            for (int i = 0; i < TM; ++i)
#pragma unroll
                for (int j = 0; j < TN; ++j) acc[i][j] += af[i] * wf[j];
        }
        __syncthreads();
    }

#pragma unroll
    for (int i = 0; i < TM; ++i) {
        const int bb = bm0 + ty * TM + i;
#pragma unroll
        for (int j = 0; j < TN; ++j) {
            const int n = bn0 + tx * TN + j;
            float v = acc[i][j] + bias[n];
            const size_t idx = (size_t)bb * N + n;
            Cout[idx] = v;
            unsigned short hh, ll;
            split1(v, hh, ll);
            Chi[idx] = hh;
            Clo[idx] = ll;
        }
    }
}

// Fused xproj + dt-proj + softplus + SSM update + einsum + gate. One block per b.
__global__ __launch_bounds__(256) void bc_kernel(
    const float* __restrict__ x,
    const float* __restrict__ z,
    const float* __restrict__ xproj_w,
    const float* __restrict__ dtproj_w,
    const float* __restrict__ dtproj_b,
    const float* __restrict__ A_log,
    const float* __restrict__ Dp,
    const float* __restrict__ ssm,
    float* __restrict__ y,
    ushort_t* __restrict__ yhi, ushort_t* __restrict__ ylo)
{
    const int b = blockIdx.x;
    const int tid = threadIdx.x;
    __shared__ __align__(16) float xs[D_INNER];
    __shared__ float xdb[XDB_DIM];

    const float4* xrow = (const float4*)(x + (size_t)b * D_INNER);
    float4* xs4 = (float4*)xs;
    for (int i = tid; i < D_INNER / 4; i += 256) xs4[i] = xrow[i];
    __syncthreads();

    const int lane = tid & 63;
    const int wv = tid >> 6;
    for (int n = wv; n < XDB_DIM; n += 4) {
        const float4* wr = (const float4*)(xproj_w + (size_t)n * D_INNER);
        float s = 0.f;
#pragma unroll
        for (int j = 0; j < D_INNER / 4 / 64; ++j) {
            float4 w = wr[lane + 64 * j];
            float4 xv = xs4[lane + 64 * j];
            s += w.x * xv.x + w.y * xv.y + w.z * xv.z + w.w * xv.w;
        }
#pragma unroll
        for (int off = 32; off > 0; off >>= 1) s += __shfl_xor(s, off);
        if (lane == 0) xdb[n] = s;
    }
    __syncthreads();

    float Bmv[D_STATE], Cv[D_STATE];
#pragma unroll
    for (int n = 0; n < D_STATE; ++n) {
        Bmv[n] = xdb[DT_RANK + n];
        Cv[n] = xdb[DT_RANK + D_STATE + n];
    }

    for (int d = tid; d < D_INNER; d += 256) {
        const float4* dtw = (const float4*)(dtproj_w + (size_t)d * DT_RANK);
        float s = 0.f;
#pragma unroll
        for (int j = 0; j < DT_RANK / 4; ++j) {
            float4 w = dtw[j];
            s += w.x * xdb[4 * j + 0] + w.y * xdb[4 * j + 1]
               + w.z * xdb[4 * j + 2] + w.w * xdb[4 * j + 3];
        }
        s += dtproj_b[d];
        float dt = fmaxf(s, 0.f) + log1pf(expf(-fabsf(s)));
        float xv = xs[d];
        float dtx = dt * xv;

        const float4* ssp = (const float4*)(ssm + ((size_t)b * D_INNER + d) * D_STATE);
        const float4* alp = (const float4*)(A_log + (size_t)d * D_STATE);
        float yacc = 0.f;
#pragma unroll
        for (int q = 0; q < 4; ++q) {
            float4 al = alp[q];
            float4 sv = ssp[q];
            float e0 = expf(-dt * expf(al.x));
            float e1 = expf(-dt * expf(al.y));
            float e2 = expf(-dt * expf(al.z));
            float e3 = expf(-dt * expf(al.w));
            yacc += (sv.x * e0 + dtx * Bmv[4 * q + 0]) * Cv[4 * q + 0];
            yacc += (sv.y * e1 + dtx * Bmv[4 * q + 1]) * Cv[4 * q + 1];
            yacc += (sv.z * e2 + dtx * Bmv[4 * q + 2]) * Cv[4 * q + 2];
            yacc += (sv.w * e3 + dtx * Bmv[4 * q + 3]) * Cv[4 * q + 3];
        }
        yacc += Dp[d] * xv;
        float zv = z[(size_t)b * D_INNER + d];
        float out = yacc * (zv * sigmoidf_(zv));
        const size_t idx = (size_t)b * D_INNER + d;
        y[idx] = out;
        unsigned short hh, ll;
        split1(out, hh, ll);
        yhi[idx] = hh;
        ylo[idx] = ll;
    }
}

__global__ __launch_bounds__(256) void ln_kernel(
    const float* __restrict__ h, const float* __restrict__ g,
    const float* __restrict__ be, float* __restrict__ out)
{
    const int b = blockIdx.x;
    const int tid = threadIdx.x;
    float v[3];
#pragma unroll
    for (int j = 0; j < 3; ++j) v[j] = h[(size_t)b * D_MODEL + tid + j * 256];
    float s = v[0] + v[1] + v[2];
    float s2 = v[0] * v[0] + v[1] * v[1] + v[2] * v[2];
#pragma unroll
    for (int off = 32; off > 0; off >>= 1) {
        s += __shfl_xor(s, off);
        s2 += __shfl_xor(s2, off);
    }
    __shared__ float red[8];
    const int lane = tid & 63, wv = tid >> 6;
    if (lane == 0) { red[wv] = s; red[4 + wv] = s2; }
    __syncthreads();
    s = red[0] + red[1] + red[2] + red[3];
    s2 = red[4] + red[5] + red[6] + red[7];
    const float mu = s * (1.f / D_MODEL);
    const float var = s2 * (1.f / D_MODEL) - mu * mu;
    const float inv = 1.f / sqrtf(var + 1e-5f);
#pragma unroll
    for (int j = 0; j < 3; ++j) {
        int c = tid + j * 256;
        out[(size_t)b * D_MODEL + c] = (v[j] - mu) * inv * g[c] + be[c];
    }
}

extern "C" void kernel_launch(void* const* d_in, const int* in_sizes, int n_in,
                              void* d_out, int out_size, void* d_ws, size_t ws_size,
                              hipStream_t stream)
{
    const float* x_t        = (const float*)d_in[0];
    const float* in_w       = (const float*)d_in[1];
    const float* in_b       = (const float*)d_in[2];
    const float* xz_w       = (const float*)d_in[3];
    const float* conv_w     = (const float*)d_in[4];
    const float* conv_b     = (const float*)d_in[5];
    const float* xproj_w    = (const float*)d_in[6];
    const float* dtproj_w   = (const float*)d_in[7];
    const float* dtproj_b   = (const float*)d_in[8];
    const float* A_log      = (const float*)d_in[9];
    const float* Dvec       = (const float*)d_in[10];
    const float* outproj_w  = (const float*)d_in[11];
    const float* conv_state = (const float*)d_in[12];
    const float* ssm_state  = (const float*)d_in[13];
    const float* ln_g       = (const float*)d_in[14];
    const float* ln_b       = (const float*)d_in[15];

    float* ws = (float*)d_ws;
    float* h = ws;                                   // 512*768
    float* x = h + (size_t)BATCH * D_MODEL;          // 512*1536
    float* z = x + (size_t)BATCH * D_INNER;
    float* y = z + (size_t)BATCH * D_INNER;
    ushort_t* us = (ushort_t*)(y + (size_t)BATCH * D_INNER);
    ushort_t* h_hi   = us;                                       // 512*768
    ushort_t* h_lo   = h_hi + (size_t)BATCH * D_MODEL;
    ushort_t* y_hi   = h_lo + (size_t)BATCH * D_MODEL;           // 512*1536
    ushort_t* y_lo   = y_hi + (size_t)BATCH * D_INNER;
    ushort_t* xzw_hi = y_lo + (size_t)BATCH * D_INNER;           // 24*3072*768
    ushort_t* xzw_lo = xzw_hi + (size_t)DEPTH * 2 * D_INNER * D_MODEL;
    ushort_t* opw_hi = xzw_lo + (size_t)DEPTH * 2 * D_INNER * D_MODEL;  // 24*768*1536
    ushort_t* opw_lo = opw_hi + (size_t)DEPTH * D_MODEL * D_INNER;

    dim3 blk(256);

    // One-time weight splits
    prep_split<<<dim3(2048), blk, 0, stream>>>(
        xz_w, xzw_hi, xzw_lo, (long)DEPTH * 2 * D_INNER * D_MODEL / 8);
    prep_split<<<dim3(2048), blk, 0, stream>>>(
        outproj_w, opw_hi, opw_lo, (long)DEPTH * D_MODEL * D_INNER / 8);

    // in_proj: h = x_t @ in_w^T + in_b (M=512, N=768, K=64), writes split planes
    gemm_k<4, 4><<<dim3(D_MODEL / 64, BATCH / 64), blk, 0, stream>>>(
        x_t, in_w, in_b, h, h_hi, h_lo, BATCH, D_MODEL, D_IN);

    for (int l = 0; l < DEPTH; ++l) {
        const ushort_t* xzh = xzw_hi + (size_t)l * 2 * D_INNER * D_MODEL;
        const ushort_t* xzl = xzw_lo + (size_t)l * 2 * D_INNER * D_MODEL;
        const ushort_t* oph = opw_hi + (size_t)l * D_MODEL * D_INNER;
        const ushort_t* opl = opw_lo + (size_t)l * D_MODEL * D_INNER;
        const float* csl = conv_state + (size_t)l * BATCH * D_INNER * D_CONV;
        const float* cwl = conv_w + (size_t)l * D_INNER * D_CONV;
        const float* cbl = conv_b + (size_t)l * D_INNER;
        const float* xpl = xproj_w + (size_t)l * XDB_DIM * D_INNER;
        const float* dwl = dtproj_w + (size_t)l * D_INNER * DT_RANK;
        const float* dbl = dtproj_b + (size_t)l * D_INNER;
        const float* all = A_log + (size_t)l * D_INNER * D_STATE;
        const float* dpl = Dvec + (size_t)l * D_INNER;
        const float* ssl = ssm_state + (size_t)l * BATCH * D_INNER * D_STATE;

        // xz = h @ xz_w^T with fused conv+silu epilogue (M=512, N=3072, K=768)
        mfma_gemm2<true><<<dim3(2 * D_INNER / 64, BATCH / 64), blk, 0, stream>>>(
            h_hi, h_lo, xzh, xzl, x, z, nullptr, nullptr,
            csl, cwl, cbl, 2 * D_INNER, D_MODEL);

        // xproj + dt + ssm + gate -> y (+ split planes)
        bc_kernel<<<dim3(BATCH), blk, 0, stream>>>(
            x, z, xpl, dwl, dbl, all, dpl, ssl, y, y_hi, y_lo);

        // h = y @ outproj_w^T (M=512, N=768, K=1536), writes h + split planes
        mfma_gemm2<false><<<dim3(D_MODEL / 64, BATCH / 64), blk, 0, stream>>>(
            y_hi, y_lo, oph, opl, h, nullptr, h_hi, h_lo,
            nullptr, nullptr, nullptr, D_MODEL, D_INNER);
    }

    ln_kernel<<<dim3(BATCH), blk, 0, stream>>>(h, ln_g, ln_b, (float*)d_out);
}